// Round 6
// baseline (222.625 us; speedup 1.0000x reference)
//
#include <hip/hip_runtime.h>

// RetrievalHeadPyramidBottomUpInstantSimple
// feat0 [32,256,56,56], feat1 [32,512,28,28], feat2 [32,1024,14,14],
// feat3 [32,2048,7,7], conv_w [1024,3840]  (all fp32) -> out [32,1024] fp32
//
// Identity: integer-factor bilinear half-pixel upsample has uniform weight
// column sums -> mean(upsample(f)) == mean(f).  So:
//   out = concat_l(spatial_mean(feat_l)) @ conv_w^T
//
// R13: single-path read rates are pinned (default-allocate 2.6 TB/s, nt
// 3.64 TB/s; sc0|sc1|nt == nt). Last lever: PATH PARALLELISM — f2+f3
// (38.5 MB, L3-resident across iterations; old runs showed 99 MB/iter
// L3-served) via default allocating loads, f0+f1 (150.5 MB) via nt HBM
// stream, with roles INTERLEAVED by bid parity so both paths are active
// simultaneously. If paths add: pool ~53 -> ~41-46 us.

typedef float vf4 __attribute__((ext_vector_type(4)));

__device__ __forceinline__ float4 ldnt(const float4* p)
{
    vf4 r = __builtin_nontemporal_load(reinterpret_cast<const vf4*>(p));
    return make_float4(r.x, r.y, r.z, r.w);
}

#if defined(__has_builtin)
# if __has_builtin(__builtin_amdgcn_make_buffer_rsrc) && __has_builtin(__builtin_amdgcn_raw_buffer_load_b128)
#  define BUF_PATH 1
# else
#  define BUF_PATH 0
# endif
#else
# define BUF_PATH 0
#endif

// aux/CPol 19 = SC0(1) | NT(2) | SC1(16): stream read-around caches.
#if BUF_PATH == 1
__device__ __forceinline__ __amdgpu_buffer_rsrc_t mkrsrc(const void* p)
{
    return __builtin_amdgcn_make_buffer_rsrc(const_cast<void*>(p),
                                             (short)0, 0xFFFFFFFFu, 0x00020000);
}
__device__ __forceinline__ float4 ldb(__amdgpu_buffer_rsrc_t r, unsigned off)
{
    auto d = __builtin_amdgcn_raw_buffer_load_b128(r, off, 0, 19);
    float4 res;
    __builtin_memcpy(&res, &d, 16);
    return res;
}
#else
__device__ __forceinline__ const char* mkrsrc(const void* p) { return (const char*)p; }
__device__ __forceinline__ float4 ldb(const char* r, unsigned off)
{
    return ldnt((const float4*)(r + off));
}
#endif

__device__ __forceinline__ float s4(float4 a) { return (a.x + a.y) + (a.z + a.w); }

// load one 3136-float chunk (784 f4) at byte offset `base`: 12 f4/lane + tail
template <typename R>
__device__ __forceinline__ void loadc_b(float4 (&r)[13], R rs, unsigned base, int lane)
{
    #pragma unroll
    for (int i = 0; i < 12; ++i)
        r[i] = ldb(rs, base + (unsigned)(lane * 16 + i * 1024));
    r[12] = make_float4(0.f, 0.f, 0.f, 0.f);
    if (lane < 16) r[12] = ldb(rs, base + 12288u + (unsigned)lane * 16u);
}

__device__ __forceinline__ float red_f0(const float4 (&r)[13])
{
    float s = 0.f;
    #pragma unroll
    for (int i = 0; i < 13; ++i) s += s4(r[i]);
    #pragma unroll
    for (int o = 32; o; o >>= 1) s += __shfl_xor(s, o);
    return s;
}

__device__ __forceinline__ float4 red_f1(const float4 (&r)[13], int lane)
{
    // chunk = 4 planes x 784 floats (196 f4); boundaries at f4 {196,392,588}
    float a0 = s4(r[0]) + s4(r[1]) + s4(r[2]) + (lane <  4 ? s4(r[3]) : 0.f);
    float a1 = (lane <  4 ? 0.f : s4(r[3])) + s4(r[4]) + s4(r[5])
             + (lane <  8 ? s4(r[6]) : 0.f);
    float a2 = (lane <  8 ? 0.f : s4(r[6])) + s4(r[7]) + s4(r[8])
             + (lane < 12 ? s4(r[9]) : 0.f);
    float a3 = (lane < 12 ? 0.f : s4(r[9])) + s4(r[10]) + s4(r[11]) + s4(r[12]);
    #pragma unroll
    for (int o = 32; o; o >>= 1) {
        a0 += __shfl_xor(a0, o); a1 += __shfl_xor(a1, o);
        a2 += __shfl_xor(a2, o); a3 += __shfl_xor(a3, o);
    }
    return make_float4(a0, a1, a2, a3);
}

__device__ __forceinline__ void store_f1(float* __restrict__ v, int c, float4 a, int lane)
{
    if (lane == 0) {
        int q = (c - 8192) * 4;                    // first plane id of chunk
        const float inv = 1.f / 784.f;
        *(float4*)&v[(q >> 9) * 3840 + 256 + (q & 511)] =
            make_float4(a.x * inv, a.y * inv, a.z * inv, a.w * inv);
    }
}

// ---- fused pool: 1568 blocks, A/BC roles interleaved by bid parity so the
// HBM-nt stream (f0/f1) and the L3-allocating stream (f2/f3) overlap in time.
//   bid<1536, even : role A,  aid=bid>>1 in [0,768): f0 chunks (aid<512,
//                    one plane/chunk) or f1 chunks (4 planes/chunk);
//                    4 waves/block, 4 chunks/wave, ping-pong; nt buffer loads.
//   bid<1536, odd  : role BC, cid=bid>>1 in [0,768): f2 tile (cid<512, 64
//                    planes) or f3 tile (256 planes); 12544-float tile staged
//                    into LDS with DEFAULT allocating loads (L3-resident).
//   bid>=1536      : zero out[32,1024] so the GEMM can atomicAdd into it.
__global__ __launch_bounds__(256) void pool_kernel(
    const float* __restrict__ f0, const float* __restrict__ f1,
    const float* __restrict__ f2, const float* __restrict__ f3,
    float* __restrict__ v, float* __restrict__ out)
{
    __shared__ float4 ls4[3136];
    int t = threadIdx.x, bid = blockIdx.x;

    if (bid < 1536 && !(bid & 1)) {
        int aid = bid >> 1;                // [0, 768)
        int w = t >> 6, lane = t & 63;
        int gw = (aid << 2) | w;           // [0, 3072)
        int c0 = gw << 2;                  // first chunk, [0, 12288)

        float4 ra[13], rb[13];
        if (aid < 512) {
            // f0: one chunk == one plane
            auto rs = mkrsrc(f0);
            unsigned base = (unsigned)c0 * 12544u;
            loadc_b(ra, rs, base, lane);
            loadc_b(rb, rs, base + 12544u, lane);
            float s0 = red_f0(ra); loadc_b(ra, rs, base + 25088u, lane);
            float s1 = red_f0(rb); loadc_b(rb, rs, base + 37632u, lane);
            float s2 = red_f0(ra);
            float s3 = red_f0(rb);
            float val = (lane == 0) ? s0 : (lane == 1) ? s1 : (lane == 2) ? s2 : s3;
            if (lane < 4)
                v[(c0 >> 8) * 3840 + (c0 & 255) + lane] = val * (1.f / 3136.f);
        } else {
            // f1: one chunk == 4 planes
            auto rs = mkrsrc(f1);
            unsigned base = (unsigned)(c0 - 8192) * 12544u;
            loadc_b(ra, rs, base, lane);
            loadc_b(rb, rs, base + 12544u, lane);
            float4 a;
            a = red_f1(ra, lane); loadc_b(ra, rs, base + 25088u, lane);
            store_f1(v, c0 + 0, a, lane);
            a = red_f1(rb, lane); loadc_b(rb, rs, base + 37632u, lane);
            store_f1(v, c0 + 1, a, lane);
            a = red_f1(ra, lane);
            store_f1(v, c0 + 2, a, lane);
            a = red_f1(rb, lane);
            store_f1(v, c0 + 3, a, lane);
        }
    } else if (bid < 1536) {
        int b2 = bid >> 1;                 // [0, 768)
        float* ls = (float*)ls4;

        // DEFAULT allocating loads: keep f2/f3 (38.5 MB) L3-resident across
        // iterations and serve them from the L3 path while role-A saturates
        // the HBM-nt path.
        const float4* pp = (b2 < 512)
            ? (const float4*)(f2 + (size_t)b2 * 12544)
            : (const float4*)(f3 + (size_t)(b2 - 512) * 12544);
        #pragma unroll
        for (int i = 0; i < 12; ++i) ls4[t + (i << 8)] = pp[t + (i << 8)];
        if (t < 64) ls4[3072 + t] = pp[3072 + t];
        __syncthreads();

        if (b2 < 512) {
            // f2: 196 floats/plane, 4 threads per plane
            int pl = t >> 2, q = t & 3;
            const float* sp = ls + pl * 196 + q * 49;
            float s = 0.f;
            #pragma unroll
            for (int i = 0; i < 48; i += 2) s += sp[i] + sp[i + 1];
            s += sp[48];
            s += __shfl_xor(s, 1); s += __shfl_xor(s, 2);
            if (q == 0) {
                int P = b2 * 64 + pl;
                v[(P >> 10) * 3840 + 768 + (P & 1023)] = s * (1.f / 196.f);
            }
        } else {
            // f3: 49 floats/plane, 1 thread per plane
            const float* sp = ls + t * 49;
            float s = 0.f;
            #pragma unroll
            for (int i = 0; i < 48; i += 2) s += sp[i] + sp[i + 1];
            s += sp[48];
            int P = (b2 - 512) * 256 + t;
            v[(P >> 11) * 3840 + 1792 + (P & 2047)] = s * (1.f / 49.f);
        }
    } else {
        // zero out[32*1024] : 32 blocks x 256 threads x float4
        int idx = (bid - 1536) * 256 + t;
        ((float4*)out)[idx] = make_float4(0.f, 0.f, 0.f, 0.f);
    }
}

// GEMM: out[b,e] += sum_k v[b,k]*W[e,k]; M=32,N=1024,K=3840
// e-tile 64, split-K x32 (KT=120) -> grid 512 blocks; split-K reduction via
// device-scope atomicAdd into out (zeroed by launch 1; stream order).
#define KT 120

__global__ __launch_bounds__(256) void gemm_kernel(
    const float* __restrict__ v, const float* __restrict__ W,
    float* __restrict__ out)
{
    __shared__ float vs[32][124];
    __shared__ float wsh[64][124];
    int t = threadIdx.x;
    int et = blockIdx.x & 15, ks = blockIdx.x >> 4;
    int e0 = et << 6, k0 = ks * KT;

    // stage W tile: 64 rows x 30 f4 = 1920 f4 (read-once -> stream, nt)
    {
        auto rw = mkrsrc(W);
        float4 tmp[7];
        int row[7], c4[7];
        #pragma unroll
        for (int i = 0; i < 7; ++i) {
            int f = t + (i << 8);
            row[i] = f / 30; c4[i] = f % 30;
            tmp[i] = ldb(rw, ((unsigned)(e0 + row[i]) * 3840u
                              + (unsigned)(k0 + c4[i] * 4)) * 4u);
        }
        float4 tail; int rowt = 0, c4t = 0;
        if (t < 128) {
            int f = t + 1792;
            rowt = f / 30; c4t = f % 30;
            tail = ldb(rw, ((unsigned)(e0 + rowt) * 3840u
                            + (unsigned)(k0 + c4t * 4)) * 4u);
        }
        #pragma unroll
        for (int i = 0; i < 7; ++i)
            *(float4*)&wsh[row[i]][c4[i] * 4] = tmp[i];
        if (t < 128)
            *(float4*)&wsh[rowt][c4t * 4] = tail;
    }
    // stage v tile: 32 rows x 30 f4 = 960 f4 (v is reused 16x -> keep cached)
    {
        float4 tmp[3];
        int row[3], c4[3];
        #pragma unroll
        for (int i = 0; i < 3; ++i) {
            int f = t + (i << 8);
            row[i] = f / 30; c4[i] = f % 30;
            tmp[i] = *(const float4*)&v[row[i] * 3840 + k0 + c4[i] * 4];
        }
        float4 tail; int rowt = 0, c4t = 0;
        if (t < 192) {
            int f = t + 768;
            rowt = f / 30; c4t = f % 30;
            tail = *(const float4*)&v[rowt * 3840 + k0 + c4t * 4];
        }
        #pragma unroll
        for (int i = 0; i < 3; ++i)
            *(float4*)&vs[row[i]][c4[i] * 4] = tmp[i];
        if (t < 192)
            *(float4*)&vs[rowt][c4t * 4] = tail;
    }
    __syncthreads();

    int bg = t >> 5, eg = t & 31;
    int b0 = bg << 2;
    float acc[4][2] = {};
    #pragma unroll 5
    for (int k = 0; k < KT; k += 4) {
        float4 vv[4], ww[2];
        #pragma unroll
        for (int i = 0; i < 4; ++i) vv[i] = *(const float4*)&vs[b0 + i][k];
        #pragma unroll
        for (int j = 0; j < 2; ++j) ww[j] = *(const float4*)&wsh[eg + (j << 5)][k];
        #pragma unroll
        for (int i = 0; i < 4; ++i)
            #pragma unroll
            for (int j = 0; j < 2; ++j)
                acc[i][j] += vv[i].x * ww[j].x + vv[i].y * ww[j].y +
                             vv[i].z * ww[j].z + vv[i].w * ww[j].w;
    }

    #pragma unroll
    for (int i = 0; i < 4; ++i)
        #pragma unroll
        for (int j = 0; j < 2; ++j)
            atomicAdd(&out[(size_t)(b0 + i) * 1024 + e0 + eg + (j << 5)], acc[i][j]);
}

extern "C" void kernel_launch(void* const* d_in, const int* in_sizes, int n_in,
                              void* d_out, int out_size, void* d_ws, size_t ws_size,
                              hipStream_t stream)
{
    const float* f0 = (const float*)d_in[0];
    const float* f1 = (const float*)d_in[1];
    const float* f2 = (const float*)d_in[2];
    const float* f3 = (const float*)d_in[3];
    const float* W  = (const float*)d_in[4];
    float* out = (float*)d_out;

    float* v = (float*)d_ws;             // 32*3840 floats

    pool_kernel<<<1568, 256, 0, stream>>>(f0, f1, f2, f3, v, out);
    gemm_kernel<<<512, 256, 0, stream>>>(v, W, out);
}

// Round 7
// 210.830 us; speedup vs baseline: 1.0559x; 1.0559x over previous
//
#include <hip/hip_runtime.h>

// RetrievalHeadPyramidBottomUpInstantSimple
// feat0 [32,256,56,56], feat1 [32,512,28,28], feat2 [32,1024,14,14],
// feat3 [32,2048,7,7], conv_w [1024,3840]  (all fp32) -> out [32,1024] fp32
//
// Identity: integer-factor bilinear half-pixel upsample has uniform weight
// column sums -> mean(upsample(f)) == mean(f).  So:
//   out = concat_l(spatial_mean(feat_l)) @ conv_w^T
//
// R14 = revert to R9 (measured best, 212.4 us).  Session findings:
//  - default-allocate read path pins at 2.6 TB/s regardless of structure
//    (register/LDS/persistent/one-shot all equal) -> policy, not code shape
//  - nontemporal loads: 3.64 TB/s (the only lever that moved, -21 us)
//  - buffer sc0|sc1|nt == flat nt (214.2 ~ 212.4, noise)
//  - splitting levels across allocate+nt paths REGRESSED (222.6): paths
//    share one limit; all-nt is the floor configuration
// Ceiling accounting: pool 193MB/3.64 = 53us + gemm ~8 + fill 60 (harness)
// + ~90 harness reset/gaps ~= 210us floor; we measure 212. At roofline.

typedef float vf4 __attribute__((ext_vector_type(4)));

__device__ __forceinline__ float4 ldnt(const float4* p)
{
    vf4 r = __builtin_nontemporal_load(reinterpret_cast<const vf4*>(p));
    return make_float4(r.x, r.y, r.z, r.w);
}

__device__ __forceinline__ float s4(float4 a) { return (a.x + a.y) + (a.z + a.w); }

// load one 3136-float chunk (784 f4): 12 f4 per lane + 16-f4 tail
__device__ __forceinline__ void loadc(float4 (&r)[13], const float4* __restrict__ p, int lane)
{
    #pragma unroll
    for (int i = 0; i < 12; ++i) r[i] = ldnt(p + lane + (i << 6));
    r[12] = make_float4(0.f, 0.f, 0.f, 0.f);
    if (lane < 16) r[12] = ldnt(p + 768 + lane);
}

__device__ __forceinline__ float red_f0(const float4 (&r)[13])
{
    float s = 0.f;
    #pragma unroll
    for (int i = 0; i < 13; ++i) s += s4(r[i]);
    #pragma unroll
    for (int o = 32; o; o >>= 1) s += __shfl_xor(s, o);
    return s;
}

__device__ __forceinline__ float4 red_f1(const float4 (&r)[13], int lane)
{
    // chunk = 4 planes x 784 floats (196 f4); boundaries at f4 {196,392,588}
    float a0 = s4(r[0]) + s4(r[1]) + s4(r[2]) + (lane <  4 ? s4(r[3]) : 0.f);
    float a1 = (lane <  4 ? 0.f : s4(r[3])) + s4(r[4]) + s4(r[5])
             + (lane <  8 ? s4(r[6]) : 0.f);
    float a2 = (lane <  8 ? 0.f : s4(r[6])) + s4(r[7]) + s4(r[8])
             + (lane < 12 ? s4(r[9]) : 0.f);
    float a3 = (lane < 12 ? 0.f : s4(r[9])) + s4(r[10]) + s4(r[11]) + s4(r[12]);
    #pragma unroll
    for (int o = 32; o; o >>= 1) {
        a0 += __shfl_xor(a0, o); a1 += __shfl_xor(a1, o);
        a2 += __shfl_xor(a2, o); a3 += __shfl_xor(a3, o);
    }
    return make_float4(a0, a1, a2, a3);
}

__device__ __forceinline__ void store_f1(float* __restrict__ v, int c, float4 a, int lane)
{
    if (lane == 0) {
        int q = (c - 8192) * 4;                    // first plane id of chunk
        const float inv = 1.f / 784.f;
        *(float4*)&v[(q >> 9) * 3840 + 256 + (q & 511)] =
            make_float4(a.x * inv, a.y * inv, a.z * inv, a.w * inv);
    }
}

// ---- fused pool: 1568 blocks.
//   bid <  768 : pool_a role — f0 (8192 chunks) + f1 (4096 chunks),
//                3136 floats/chunk, 4 waves/block, 4 chunks/wave, ping-pong.
//   bid < 1536 : pool_bc role — f2 (512 tiles x 64 planes) + f3 (256 tiles
//                x 256 planes), 12544-float tile staged coalesced into LDS.
//   else       : zero out[32,1024] so the GEMM can atomicAdd into it.
__global__ __launch_bounds__(256) void pool_kernel(
    const float* __restrict__ f0, const float* __restrict__ f1,
    const float* __restrict__ f2, const float* __restrict__ f3,
    float* __restrict__ v, float* __restrict__ out)
{
    __shared__ float4 ls4[3136];
    int t = threadIdx.x, bid = blockIdx.x;

    if (bid < 768) {
        int w = t >> 6, lane = t & 63;
        int gw = (bid << 2) | w;           // [0, 3072)
        int c0 = gw << 2;                  // first chunk, [0, 12288)

        const float4* p = (c0 < 8192)
            ? (const float4*)(f0 + (size_t)c0 * 3136)
            : (const float4*)(f1 + (size_t)(c0 - 8192) * 3136);

        float4 ra[13], rb[13];
        loadc(ra, p, lane);                // chunk c0
        loadc(rb, p + 784, lane);          // chunk c0+1

        if (c0 < 8192) {
            float s0 = red_f0(ra); loadc(ra, p + 1568, lane);
            float s1 = red_f0(rb); loadc(rb, p + 2352, lane);
            float s2 = red_f0(ra);
            float s3 = red_f0(rb);
            float val = (lane == 0) ? s0 : (lane == 1) ? s1 : (lane == 2) ? s2 : s3;
            if (lane < 4)
                v[(c0 >> 8) * 3840 + (c0 & 255) + lane] = val * (1.f / 3136.f);
        } else {
            float4 a;
            a = red_f1(ra, lane); loadc(ra, p + 1568, lane);
            store_f1(v, c0 + 0, a, lane);
            a = red_f1(rb, lane); loadc(rb, p + 2352, lane);
            store_f1(v, c0 + 1, a, lane);
            a = red_f1(ra, lane);
            store_f1(v, c0 + 2, a, lane);
            a = red_f1(rb, lane);
            store_f1(v, c0 + 3, a, lane);
        }
    } else if (bid < 1536) {
        int b2 = bid - 768;
        float* ls = (float*)ls4;

        const float4* pp = (b2 < 512)
            ? (const float4*)(f2 + (size_t)b2 * 12544)
            : (const float4*)(f3 + (size_t)(b2 - 512) * 12544);
        #pragma unroll
        for (int i = 0; i < 12; ++i) ls4[t + (i << 8)] = ldnt(pp + t + (i << 8));
        if (t < 64) ls4[3072 + t] = ldnt(pp + 3072 + t);
        __syncthreads();

        if (b2 < 512) {
            // f2: 196 floats/plane, 4 threads per plane
            int pl = t >> 2, q = t & 3;
            const float* sp = ls + pl * 196 + q * 49;
            float s = 0.f;
            #pragma unroll
            for (int i = 0; i < 48; i += 2) s += sp[i] + sp[i + 1];
            s += sp[48];
            s += __shfl_xor(s, 1); s += __shfl_xor(s, 2);
            if (q == 0) {
                int P = b2 * 64 + pl;
                v[(P >> 10) * 3840 + 768 + (P & 1023)] = s * (1.f / 196.f);
            }
        } else {
            // f3: 49 floats/plane, 1 thread per plane
            const float* sp = ls + t * 49;
            float s = 0.f;
            #pragma unroll
            for (int i = 0; i < 48; i += 2) s += sp[i] + sp[i + 1];
            s += sp[48];
            int P = (b2 - 512) * 256 + t;
            v[(P >> 11) * 3840 + 1792 + (P & 2047)] = s * (1.f / 49.f);
        }
    } else {
        // zero out[32*1024] : 32 blocks x 256 threads x float4
        int idx = (bid - 1536) * 256 + t;
        ((float4*)out)[idx] = make_float4(0.f, 0.f, 0.f, 0.f);
    }
}

// GEMM: out[b,e] += sum_k v[b,k]*W[e,k]; M=32,N=1024,K=3840
// e-tile 64, split-K x32 (KT=120) -> grid 512 blocks; split-K reduction via
// device-scope atomicAdd into out (zeroed by launch 1; stream order).
#define KT 120

__global__ __launch_bounds__(256) void gemm_kernel(
    const float* __restrict__ v, const float* __restrict__ W,
    float* __restrict__ out)
{
    __shared__ float vs[32][124];
    __shared__ float wsh[64][124];
    int t = threadIdx.x;
    int et = blockIdx.x & 15, ks = blockIdx.x >> 4;
    int e0 = et << 6, k0 = ks * KT;

    // stage W tile: 64 rows x 30 f4 = 1920 f4 (read-once -> nontemporal)
    {
        float4 tmp[7];
        int row[7], c4[7];
        #pragma unroll
        for (int i = 0; i < 7; ++i) {
            int f = t + (i << 8);
            row[i] = f / 30; c4[i] = f % 30;
            tmp[i] = ldnt((const float4*)&W[(size_t)(e0 + row[i]) * 3840 + k0 + c4[i] * 4]);
        }
        float4 tail; int rowt = 0, c4t = 0;
        if (t < 128) {
            int f = t + 1792;
            rowt = f / 30; c4t = f % 30;
            tail = ldnt((const float4*)&W[(size_t)(e0 + rowt) * 3840 + k0 + c4t * 4]);
        }
        #pragma unroll
        for (int i = 0; i < 7; ++i)
            *(float4*)&wsh[row[i]][c4[i] * 4] = tmp[i];
        if (t < 128)
            *(float4*)&wsh[rowt][c4t * 4] = tail;
    }
    // stage v tile: 32 rows x 30 f4 = 960 f4 (v is reused 16x -> keep cached)
    {
        float4 tmp[3];
        int row[3], c4[3];
        #pragma unroll
        for (int i = 0; i < 3; ++i) {
            int f = t + (i << 8);
            row[i] = f / 30; c4[i] = f % 30;
            tmp[i] = *(const float4*)&v[row[i] * 3840 + k0 + c4[i] * 4];
        }
        float4 tail; int rowt = 0, c4t = 0;
        if (t < 192) {
            int f = t + 768;
            rowt = f / 30; c4t = f % 30;
            tail = *(const float4*)&v[rowt * 3840 + k0 + c4t * 4];
        }
        #pragma unroll
        for (int i = 0; i < 3; ++i)
            *(float4*)&vs[row[i]][c4[i] * 4] = tmp[i];
        if (t < 192)
            *(float4*)&vs[rowt][c4t * 4] = tail;
    }
    __syncthreads();

    int bg = t >> 5, eg = t & 31;
    int b0 = bg << 2;
    float acc[4][2] = {};
    #pragma unroll 5
    for (int k = 0; k < KT; k += 4) {
        float4 vv[4], ww[2];
        #pragma unroll
        for (int i = 0; i < 4; ++i) vv[i] = *(const float4*)&vs[b0 + i][k];
        #pragma unroll
        for (int j = 0; j < 2; ++j) ww[j] = *(const float4*)&wsh[eg + (j << 5)][k];
        #pragma unroll
        for (int i = 0; i < 4; ++i)
            #pragma unroll
            for (int j = 0; j < 2; ++j)
                acc[i][j] += vv[i].x * ww[j].x + vv[i].y * ww[j].y +
                             vv[i].z * ww[j].z + vv[i].w * ww[j].w;
    }

    #pragma unroll
    for (int i = 0; i < 4; ++i)
        #pragma unroll
        for (int j = 0; j < 2; ++j)
            atomicAdd(&out[(size_t)(b0 + i) * 1024 + e0 + eg + (j << 5)], acc[i][j]);
}

extern "C" void kernel_launch(void* const* d_in, const int* in_sizes, int n_in,
                              void* d_out, int out_size, void* d_ws, size_t ws_size,
                              hipStream_t stream)
{
    const float* f0 = (const float*)d_in[0];
    const float* f1 = (const float*)d_in[1];
    const float* f2 = (const float*)d_in[2];
    const float* f3 = (const float*)d_in[3];
    const float* W  = (const float*)d_in[4];
    float* out = (float*)d_out;

    float* v = (float*)d_ws;             // 32*3840 floats

    pool_kernel<<<1568, 256, 0, stream>>>(f0, f1, f2, f3, v, out);
    gemm_kernel<<<512, 256, 0, stream>>>(v, W, out);
}